// Round 4
// baseline (16218.933 us; speedup 1.0000x reference)
//
#include <hip/hip_runtime.h>
#include <math.h>

#define SS   256
#define BB   128
#define INN  256
#define HH   256
#define NG   1024   // 4*H
#define NL   2
#define EPSV 1e-5f

__device__ __forceinline__ float sum4(float4 v)   { return v.x + v.y + v.z + v.w; }
__device__ __forceinline__ float sumsq4(float4 v) { return v.x*v.x + v.y*v.y + v.z*v.z + v.w*v.w; }
__device__ __forceinline__ float fast_sigmoid(float x) { return 1.0f / (1.0f + __expf(-x)); }
__device__ __forceinline__ float fast_tanh(float x) {
  float t = __expf(-2.0f * fabsf(x));
  float r = (1.0f - t) / (1.0f + t);
  return copysignf(r, x);
}

__global__ void init_state(const float* __restrict__ h0, const float* __restrict__ c0,
                           float* __restrict__ hs, float* __restrict__ cs, int n) {
  int i = blockIdx.x * blockDim.x + threadIdx.x;
  if (i < n) { hs[i] = h0[i]; cs[i] = c0[i]; }
}

// C[M x NG] = A[M x 256] * W[256 x NG]. Raw output (LN fused later). M = nt*BB per chunk.
// 128x128 tile, 256 threads, 8x8 micro-tile, K-slice 16.
__global__ __launch_bounds__(256) void gemm_gx(const float* __restrict__ A,
                                               const float* __restrict__ W,
                                               float* __restrict__ C) {
  __shared__ __align__(16) float As[16][132];   // [k][m]
  __shared__ __align__(16) float Bs[16][132];   // [k][n]
  const int tid = threadIdx.x;
  const int bn  = blockIdx.x * 128;
  const int bm  = blockIdx.y * 128;
  const int tx  = tid & 15;          // output col group (8 cols)
  const int ty  = tid >> 4;          // output row group (8 rows)
  const int am  = tid >> 1;          // A row in tile (0..127)
  const int ac  = (tid & 1) << 3;    // A k offset (0 or 8)
  const int br  = tid >> 4;          // B k row (0..15)
  const int bc  = (tid & 15) << 2;   // B col (0,4,...,60)

  float acc[8][8] = {};
  for (int k0 = 0; k0 < INN; k0 += 16) {
    const float4 a0 = *(const float4*)&A[(size_t)(bm + am) * INN + k0 + ac];
    const float4 a1 = *(const float4*)&A[(size_t)(bm + am) * INN + k0 + ac + 4];
    const float4 b0 = *(const float4*)&W[(size_t)(k0 + br) * NG + bn + bc];
    const float4 b1 = *(const float4*)&W[(size_t)(k0 + br) * NG + bn + bc + 64];
    __syncthreads();
    As[ac + 0][am] = a0.x; As[ac + 1][am] = a0.y; As[ac + 2][am] = a0.z; As[ac + 3][am] = a0.w;
    As[ac + 4][am] = a1.x; As[ac + 5][am] = a1.y; As[ac + 6][am] = a1.z; As[ac + 7][am] = a1.w;
    *(float4*)&Bs[br][bc]      = b0;
    *(float4*)&Bs[br][bc + 64] = b1;
    __syncthreads();
#pragma unroll
    for (int k = 0; k < 16; ++k) {
      const float4 av0 = *(const float4*)&As[k][ty << 3];
      const float4 av1 = *(const float4*)&As[k][(ty << 3) + 4];
      const float4 bv0 = *(const float4*)&Bs[k][tx << 3];
      const float4 bv1 = *(const float4*)&Bs[k][(tx << 3) + 4];
      const float a[8] = {av0.x, av0.y, av0.z, av0.w, av1.x, av1.y, av1.z, av1.w};
      const float b[8] = {bv0.x, bv0.y, bv0.z, bv0.w, bv1.x, bv1.y, bv1.z, bv1.w};
#pragma unroll
      for (int i = 0; i < 8; ++i)
#pragma unroll
        for (int j = 0; j < 8; ++j) acc[i][j] += a[i] * b[j];
    }
  }
#pragma unroll
  for (int i = 0; i < 8; ++i) {
    const size_t row = (size_t)(bm + (ty << 3) + i) * NG + bn + (tx << 3);
    float4 o0 = {acc[i][0], acc[i][1], acc[i][2], acc[i][3]};
    float4 o1 = {acc[i][4], acc[i][5], acc[i][6], acc[i][7]};
    *(float4*)&C[row]     = o0;
    *(float4*)&C[row + 4] = o1;
  }
}

// Persistent per-layer scan over a chunk of nsteps. Each block owns ONE batch row;
// thread t owns gate columns 4t..4t+3 during the dot/LN phase and hidden unit t
// during the cell update. Deep register double-buffer keeps ~16KB/wave of wh
// loads in flight (round-3 counters showed the compiler alone leaves us at
// ~46 GB/s/CU, pure latency stall: VALUBusy 3.7%, VGPR 56).
__global__ __launch_bounds__(256, 1) void lstm_rec(
    const float* __restrict__ gx,     // [nsteps][B][NG] raw x-projection (chunk-local)
    const float* __restrict__ whl,    // [H][NG]
    float* __restrict__ hsl,          // [B][H] running h state (also final output slot)
    float* __restrict__ csl,          // [B][H] running c state (also final output slot)
    const float* __restrict__ gam,    // [2*NG] (gx gamma | gh gamma)
    const float* __restrict__ bet,    // [2*NG]
    const float* __restrict__ bias,   // [NG]
    float* __restrict__ ys,           // [S][B][H] full-sequence output
    int t0, int nsteps)
{
  __shared__ __align__(16) float hbuf[HH];
  __shared__ __align__(16) float gex[NG];
  __shared__ float red[4][4];

  const int tid = threadIdx.x;
  const int b   = blockIdx.x;        // one batch row per block
  const int lane = tid & 63;
  const int wid  = tid >> 6;

  // per-column constants (cols 4t..4t+3)
  const float4 gxg = *(const float4*)&gam[4 * tid];
  const float4 gxb = *(const float4*)&bet[4 * tid];
  const float4 ghg = *(const float4*)&gam[NG + 4 * tid];
  const float4 ghb = *(const float4*)&bet[NG + 4 * tid];
  const float4 bi  = *(const float4*)&bias[4 * tid];

  float c = csl[b * HH + tid];
  hbuf[tid] = hsl[b * HH + tid];
  __syncthreads();

  const float4* w4 = (const float4*)whl;  // [256 rows][256 float4], row stride 256

  for (int t = 0; t < nsteps; ++t) {
    // prefetch this step's raw gx row (HBM-streamed; hides under the dot)
    const float4 x0 = *(const float4*)&gx[((size_t)t * BB + b) * NG + 4 * tid];

    // ---- gh(row b) cols 4t..4t+3: 16-row stages, double-buffered in registers ----
    float4 acc = {0.f, 0.f, 0.f, 0.f};
    float4 wA[16], wB[16];
#pragma unroll
    for (int j = 0; j < 16; ++j) wA[j] = w4[j * (NG / 4) + tid];

#pragma unroll
    for (int s = 0; s < 8; ++s) {          // 8 double-stages of 32 k-rows
      const int kA = s * 32;
      // issue B-stage loads (rows kA+16 .. kA+31)
#pragma unroll
      for (int j = 0; j < 16; ++j) wB[j] = w4[(kA + 16 + j) * (NG / 4) + tid];
      // compute with A-stage (rows kA .. kA+15)
#pragma unroll
      for (int j = 0; j < 16; j += 4) {
        const float4 h4 = *(const float4*)&hbuf[kA + j];
        acc.x += h4.x * wA[j].x + h4.y * wA[j+1].x + h4.z * wA[j+2].x + h4.w * wA[j+3].x;
        acc.y += h4.x * wA[j].y + h4.y * wA[j+1].y + h4.z * wA[j+2].y + h4.w * wA[j+3].y;
        acc.z += h4.x * wA[j].z + h4.y * wA[j+1].z + h4.z * wA[j+2].z + h4.w * wA[j+3].z;
        acc.w += h4.x * wA[j].w + h4.y * wA[j+1].w + h4.z * wA[j+2].w + h4.w * wA[j+3].w;
      }
      // issue next A-stage loads (rows kA+32 .. kA+47)
      if (s < 7) {
#pragma unroll
        for (int j = 0; j < 16; ++j) wA[j] = w4[(kA + 32 + j) * (NG / 4) + tid];
      }
      // compute with B-stage (rows kA+16 .. kA+31)
#pragma unroll
      for (int j = 0; j < 16; j += 4) {
        const float4 h4 = *(const float4*)&hbuf[kA + 16 + j];
        acc.x += h4.x * wB[j].x + h4.y * wB[j+1].x + h4.z * wB[j+2].x + h4.w * wB[j+3].x;
        acc.y += h4.x * wB[j].y + h4.y * wB[j+1].y + h4.z * wB[j+2].y + h4.w * wB[j+3].y;
        acc.z += h4.x * wB[j].z + h4.y * wB[j+1].z + h4.z * wB[j+2].z + h4.w * wB[j+3].z;
        acc.w += h4.x * wB[j].w + h4.y * wB[j+1].w + h4.z * wB[j+2].w + h4.w * wB[j+3].w;
      }
    }

    // ---- LN stats for this row: {sum,sumsq} x {gh, gx} ----
    float v[4] = {sum4(acc), sumsq4(acc), sum4(x0), sumsq4(x0)};
#pragma unroll
    for (int off = 32; off; off >>= 1)
#pragma unroll
      for (int j = 0; j < 4; ++j) v[j] += __shfl_xor(v[j], off);
    if (lane == 0) {
#pragma unroll
      for (int j = 0; j < 4; ++j) red[wid][j] = v[j];
    }
    __syncthreads();
    float s0 = red[0][0] + red[1][0] + red[2][0] + red[3][0];
    float s1 = red[0][1] + red[1][1] + red[2][1] + red[3][1];
    float s2 = red[0][2] + red[1][2] + red[2][2] + red[3][2];
    float s3 = red[0][3] + red[1][3] + red[2][3] + red[3][3];

    const float inv = 1.0f / (float)NG;
    const float muh = s0 * inv, mux = s2 * inv;
    const float rsh = rsqrtf(s1 * inv - muh * muh + EPSV);
    const float rsx = rsqrtf(s3 * inv - mux * mux + EPSV);

    // ---- gate pre-activations for cols 4t..4t+3 ----
    float4 g0;
    g0.x = (x0.x - mux) * rsx * gxg.x + gxb.x + (acc.x - muh) * rsh * ghg.x + ghb.x + bi.x;
    g0.y = (x0.y - mux) * rsx * gxg.y + gxb.y + (acc.y - muh) * rsh * ghg.y + ghb.y + bi.y;
    g0.z = (x0.z - mux) * rsx * gxg.z + gxb.z + (acc.z - muh) * rsh * ghg.z + ghb.z + bi.z;
    g0.w = (x0.w - mux) * rsx * gxg.w + gxb.w + (acc.w - muh) * rsh * ghg.w + ghb.w + bi.w;
    *(float4*)&gex[4 * tid] = g0;
    __syncthreads();

    // ---- thread t gathers i,f,o,g for hidden unit t and updates state ----
    {
      const float gi = gex[tid];
      const float gf = gex[256 + tid];
      const float go = gex[512 + tid];
      const float gg = gex[768 + tid];
      const float ii = fast_sigmoid(gi);
      const float ff = fast_sigmoid(gf);
      const float oo = fast_sigmoid(go);
      const float g  = fast_tanh(gg);
      const float cn = ff * c + ii * g;
      const float hn = oo * fast_tanh(cn);
      c = cn;
      __syncthreads();            // everyone done reading gex & old hbuf
      hbuf[tid] = hn;
      ys[((size_t)(t0 + t) * BB + b) * HH + tid] = hn;
    }
    __syncthreads();  // hbuf ready for next step
  }

  // write back running state (after last chunk this IS the hT/cT output)
  hsl[b * HH + tid] = hbuf[tid];
  csl[b * HH + tid] = c;
}

extern "C" void kernel_launch(void* const* d_in, const int* in_sizes, int n_in,
                              void* d_out, int out_size, void* d_ws, size_t ws_size,
                              hipStream_t stream) {
  const float* x    = (const float*)d_in[0];
  const float* h0   = (const float*)d_in[1];
  const float* c0   = (const float*)d_in[2];
  const float* wx   = (const float*)d_in[3];
  const float* wh   = (const float*)d_in[4];
  const float* bias = (const float*)d_in[5];
  const float* gam  = (const float*)d_in[6];
  const float* bet  = (const float*)d_in[7];

  float* out  = (float*)d_out;
  float* ys_x = out;                                  // [S][B][H]: ys0 scratch, then final x
  float* hs   = out + (size_t)SS * BB * HH;           // [L][B][H] (doubles as running h state)
  float* cs   = hs + (size_t)NL * BB * HH;            // [L][B][H] (doubles as running c state)
  float* gxbuf = (float*)d_ws;                        // up to [S][B][NG] = 128 MiB

  // chunk the time axis to whatever the workspace can hold
  const size_t step_bytes = (size_t)BB * NG * sizeof(float);
  int T = (int)(ws_size / step_bytes);
  if (T > SS) T = SS;
  if (T < 1)  T = 1;

  const int nstate = NL * BB * HH;
  init_state<<<(nstate + 255) / 256, 256, 0, stream>>>(h0, c0, hs, cs, nstate);

  for (int l = 0; l < NL; ++l) {
    const float* Ain = (l == 0) ? x : ys_x;
    for (int t0 = 0; t0 < SS; t0 += T) {
      const int nt = (SS - t0 < T) ? (SS - t0) : T;
      const dim3 ggrid(NG / 128, nt);   // M = nt*BB rows, 128 rows/block
      gemm_gx<<<ggrid, 256, 0, stream>>>(Ain + (size_t)t0 * BB * INN,
                                         wx + (size_t)l * INN * NG, gxbuf);
      lstm_rec<<<BB, 256, 0, stream>>>(
          gxbuf, wh + (size_t)l * HH * NG,
          hs + (size_t)l * BB * HH, cs + (size_t)l * BB * HH,
          gam + (size_t)l * 2 * NG, bet + (size_t)l * 2 * NG,
          bias + (size_t)l * NG, ys_x, t0, nt);
    }
  }
}

// Round 8
// 13919.968 us; speedup vs baseline: 1.1652x; 1.1652x over previous
//
#include <hip/hip_runtime.h>
#include <math.h>

#define SS   256
#define BB   128
#define INN  256
#define HH   256
#define NG   1024   // 4*H
#define NL   2
#define EPSV 1e-5f

__device__ __forceinline__ float sum4(float4 v)   { return v.x + v.y + v.z + v.w; }
__device__ __forceinline__ float sumsq4(float4 v) { return v.x*v.x + v.y*v.y + v.z*v.z + v.w*v.w; }
__device__ __forceinline__ float fast_sigmoid(float x) { return 1.0f / (1.0f + __expf(-x)); }
__device__ __forceinline__ float fast_tanh(float x) {
  float t = __expf(-2.0f * fabsf(x));
  float r = (1.0f - t) / (1.0f + t);
  return copysignf(r, x);
}

__global__ void init_state(const float* __restrict__ h0, const float* __restrict__ c0,
                           float* __restrict__ hs, float* __restrict__ cs, int n) {
  int i = blockIdx.x * blockDim.x + threadIdx.x;
  if (i < n) { hs[i] = h0[i]; cs[i] = c0[i]; }
}

// C[M x NG] = A[M x 256] * W[256 x NG]. Raw output (LN fused later). M = nt*BB per chunk.
// 128x128 tile, 256 threads, 8x8 micro-tile, K-slice 16.
__global__ __launch_bounds__(256) void gemm_gx(const float* __restrict__ A,
                                               const float* __restrict__ W,
                                               float* __restrict__ C) {
  __shared__ __align__(16) float As[16][132];   // [k][m]
  __shared__ __align__(16) float Bs[16][132];   // [k][n]
  const int tid = threadIdx.x;
  const int bn  = blockIdx.x * 128;
  const int bm  = blockIdx.y * 128;
  const int tx  = tid & 15;          // output col group (8 cols)
  const int ty  = tid >> 4;          // output row group (8 rows)
  const int am  = tid >> 1;          // A row in tile (0..127)
  const int ac  = (tid & 1) << 3;    // A k offset (0 or 8)
  const int br  = tid >> 4;          // B k row (0..15)
  const int bc  = (tid & 15) << 2;   // B col (0,4,...,60)

  float acc[8][8] = {};
  for (int k0 = 0; k0 < INN; k0 += 16) {
    const float4 a0 = *(const float4*)&A[(size_t)(bm + am) * INN + k0 + ac];
    const float4 a1 = *(const float4*)&A[(size_t)(bm + am) * INN + k0 + ac + 4];
    const float4 b0 = *(const float4*)&W[(size_t)(k0 + br) * NG + bn + bc];
    const float4 b1 = *(const float4*)&W[(size_t)(k0 + br) * NG + bn + bc + 64];
    __syncthreads();
    As[ac + 0][am] = a0.x; As[ac + 1][am] = a0.y; As[ac + 2][am] = a0.z; As[ac + 3][am] = a0.w;
    As[ac + 4][am] = a1.x; As[ac + 5][am] = a1.y; As[ac + 6][am] = a1.z; As[ac + 7][am] = a1.w;
    *(float4*)&Bs[br][bc]      = b0;
    *(float4*)&Bs[br][bc + 64] = b1;
    __syncthreads();
#pragma unroll
    for (int k = 0; k < 16; ++k) {
      const float4 av0 = *(const float4*)&As[k][ty << 3];
      const float4 av1 = *(const float4*)&As[k][(ty << 3) + 4];
      const float4 bv0 = *(const float4*)&Bs[k][tx << 3];
      const float4 bv1 = *(const float4*)&Bs[k][(tx << 3) + 4];
      const float a[8] = {av0.x, av0.y, av0.z, av0.w, av1.x, av1.y, av1.z, av1.w};
      const float b[8] = {bv0.x, bv0.y, bv0.z, bv0.w, bv1.x, bv1.y, bv1.z, bv1.w};
#pragma unroll
      for (int i = 0; i < 8; ++i)
#pragma unroll
        for (int j = 0; j < 8; ++j) acc[i][j] += a[i] * b[j];
    }
  }
#pragma unroll
  for (int i = 0; i < 8; ++i) {
    const size_t row = (size_t)(bm + (ty << 3) + i) * NG + bn + (tx << 3);
    float4 o0 = {acc[i][0], acc[i][1], acc[i][2], acc[i][3]};
    float4 o1 = {acc[i][4], acc[i][5], acc[i][6], acc[i][7]};
    *(float4*)&C[row]     = o0;
    *(float4*)&C[row + 4] = o1;
  }
}

// Persistent per-layer scan. 64 blocks x 2 batch rows (8 blocks/XCD keeps the
// shared 1 MiB wh L2/L3-resident — round-3 counters: FETCH 69.9 MB total; at
// 128 blocks round-4 showed 10.46 GB of wh HBM refetch). Explicit 32-float4
// register double-buffer per thread keeps ~64 KB/CU of wh loads in flight
// (round-3's compiler-scheduled version stalled at VGPR=56, ~8 KB in flight,
// VALUBusy 3.7%).
__global__ __launch_bounds__(256, 1) void lstm_rec(
    const float* __restrict__ gx,     // [nsteps][B][NG] raw x-projection (chunk-local)
    const float* __restrict__ whl,    // [H][NG]
    float* __restrict__ hsl,          // [B][H] running h state (also final output slot)
    float* __restrict__ csl,          // [B][H] running c state (also final output slot)
    const float* __restrict__ gam,    // [2*NG] (gx gamma | gh gamma)
    const float* __restrict__ bet,    // [2*NG]
    const float* __restrict__ bias,   // [NG]
    float* __restrict__ ys,           // [S][B][H] full-sequence output
    int t0, int nsteps)
{
  __shared__ __align__(16) float hbuf[2][HH];
  __shared__ __align__(16) float gex[2][NG];
  __shared__ float red[4][8];

  const int tid = threadIdx.x;
  const int b0  = blockIdx.x * 2;
  const int lane = tid & 63;
  const int wid  = tid >> 6;

  // per-column constants (cols 4t..4t+3)
  const float4 gxg = *(const float4*)&gam[4 * tid];
  const float4 gxb = *(const float4*)&bet[4 * tid];
  const float4 ghg = *(const float4*)&gam[NG + 4 * tid];
  const float4 ghb = *(const float4*)&bet[NG + 4 * tid];
  const float4 bi  = *(const float4*)&bias[4 * tid];

  float c0r = csl[(b0 + 0) * HH + tid];
  float c1r = csl[(b0 + 1) * HH + tid];
  hbuf[0][tid] = hsl[(b0 + 0) * HH + tid];
  hbuf[1][tid] = hsl[(b0 + 1) * HH + tid];
  __syncthreads();

  const float4* w4 = (const float4*)whl;  // [256 rows][256 float4], row stride 256

  for (int t = 0; t < nsteps; ++t) {
    // prefetch this step's raw gx rows (independent; hides under the dot)
    const float4 x0 = *(const float4*)&gx[((size_t)t * BB + b0 + 0) * NG + 4 * tid];
    const float4 x1 = *(const float4*)&gx[((size_t)t * BB + b0 + 1) * NG + 4 * tid];

    // ---- gh cols 4t..4t+3 for both rows: 16-row stages, double-buffered ----
    float4 a0 = {0.f, 0.f, 0.f, 0.f};
    float4 a1 = {0.f, 0.f, 0.f, 0.f};
    float4 wA[16], wB[16];
#pragma unroll
    for (int j = 0; j < 16; ++j) wA[j] = w4[j * (NG / 4) + tid];

#pragma unroll
    for (int s = 0; s < 8; ++s) {          // 8 double-stages of 32 k-rows
      const int kA = s * 32;
      // issue B-stage loads (rows kA+16 .. kA+31)
#pragma unroll
      for (int j = 0; j < 16; ++j) wB[j] = w4[(kA + 16 + j) * (NG / 4) + tid];
      // compute with A-stage (rows kA .. kA+15), both batch rows
#pragma unroll
      for (int j = 0; j < 16; j += 4) {
        const float4 h40 = *(const float4*)&hbuf[0][kA + j];
        const float4 h41 = *(const float4*)&hbuf[1][kA + j];
        a0.x += h40.x * wA[j].x + h40.y * wA[j+1].x + h40.z * wA[j+2].x + h40.w * wA[j+3].x;
        a0.y += h40.x * wA[j].y + h40.y * wA[j+1].y + h40.z * wA[j+2].y + h40.w * wA[j+3].y;
        a0.z += h40.x * wA[j].z + h40.y * wA[j+1].z + h40.z * wA[j+2].z + h40.w * wA[j+3].z;
        a0.w += h40.x * wA[j].w + h40.y * wA[j+1].w + h40.z * wA[j+2].w + h40.w * wA[j+3].w;
        a1.x += h41.x * wA[j].x + h41.y * wA[j+1].x + h41.z * wA[j+2].x + h41.w * wA[j+3].x;
        a1.y += h41.x * wA[j].y + h41.y * wA[j+1].y + h41.z * wA[j+2].y + h41.w * wA[j+3].y;
        a1.z += h41.x * wA[j].z + h41.y * wA[j+1].z + h41.z * wA[j+2].z + h41.w * wA[j+3].z;
        a1.w += h41.x * wA[j].w + h41.y * wA[j+1].w + h41.z * wA[j+2].w + h41.w * wA[j+3].w;
      }
      // issue next A-stage loads (rows kA+32 .. kA+47)
      if (s < 7) {
#pragma unroll
        for (int j = 0; j < 16; ++j) wA[j] = w4[(kA + 32 + j) * (NG / 4) + tid];
      }
      // compute with B-stage (rows kA+16 .. kA+31), both batch rows
#pragma unroll
      for (int j = 0; j < 16; j += 4) {
        const float4 h40 = *(const float4*)&hbuf[0][kA + 16 + j];
        const float4 h41 = *(const float4*)&hbuf[1][kA + 16 + j];
        a0.x += h40.x * wB[j].x + h40.y * wB[j+1].x + h40.z * wB[j+2].x + h40.w * wB[j+3].x;
        a0.y += h40.x * wB[j].y + h40.y * wB[j+1].y + h40.z * wB[j+2].y + h40.w * wB[j+3].y;
        a0.z += h40.x * wB[j].z + h40.y * wB[j+1].z + h40.z * wB[j+2].z + h40.w * wB[j+3].z;
        a0.w += h40.x * wB[j].w + h40.y * wB[j+1].w + h40.z * wB[j+2].w + h40.w * wB[j+3].w;
        a1.x += h41.x * wB[j].x + h41.y * wB[j+1].x + h41.z * wB[j+2].x + h41.w * wB[j+3].x;
        a1.y += h41.x * wB[j].y + h41.y * wB[j+1].y + h41.z * wB[j+2].y + h41.w * wB[j+3].y;
        a1.z += h41.x * wB[j].z + h41.y * wB[j+1].z + h41.z * wB[j+2].z + h41.w * wB[j+3].z;
        a1.w += h41.x * wB[j].w + h41.y * wB[j+1].w + h41.z * wB[j+2].w + h41.w * wB[j+3].w;
      }
    }

    // ---- block-wide LN stats: {sum,sumsq} x {gh0,gh1,gx0,gx1} ----
    float v[8] = {sum4(a0), sumsq4(a0), sum4(a1), sumsq4(a1),
                  sum4(x0), sumsq4(x0), sum4(x1), sumsq4(x1)};
#pragma unroll
    for (int off = 32; off; off >>= 1)
#pragma unroll
      for (int j = 0; j < 8; ++j) v[j] += __shfl_xor(v[j], off);
    if (lane == 0) {
#pragma unroll
      for (int j = 0; j < 8; ++j) red[wid][j] = v[j];
    }
    __syncthreads();
    float s[8];
#pragma unroll
    for (int j = 0; j < 8; ++j)
      s[j] = red[0][j] + red[1][j] + red[2][j] + red[3][j];

    const float inv = 1.0f / (float)NG;
    const float muh0 = s[0] * inv, muh1 = s[2] * inv;
    const float mux0 = s[4] * inv, mux1 = s[6] * inv;
    const float rsh0 = rsqrtf(s[1] * inv - muh0 * muh0 + EPSV);
    const float rsh1 = rsqrtf(s[3] * inv - muh1 * muh1 + EPSV);
    const float rsx0 = rsqrtf(s[5] * inv - mux0 * mux0 + EPSV);
    const float rsx1 = rsqrtf(s[7] * inv - mux1 * mux1 + EPSV);

    // ---- gate pre-activations for cols 4t..4t+3, both rows ----
    float4 g0, g1;
    g0.x = (x0.x - mux0) * rsx0 * gxg.x + gxb.x + (a0.x - muh0) * rsh0 * ghg.x + ghb.x + bi.x;
    g0.y = (x0.y - mux0) * rsx0 * gxg.y + gxb.y + (a0.y - muh0) * rsh0 * ghg.y + ghb.y + bi.y;
    g0.z = (x0.z - mux0) * rsx0 * gxg.z + gxb.z + (a0.z - muh0) * rsh0 * ghg.z + ghb.z + bi.z;
    g0.w = (x0.w - mux0) * rsx0 * gxg.w + gxb.w + (a0.w - muh0) * rsh0 * ghg.w + ghb.w + bi.w;
    g1.x = (x1.x - mux1) * rsx1 * gxg.x + gxb.x + (a1.x - muh1) * rsh1 * ghg.x + ghb.x + bi.x;
    g1.y = (x1.y - mux1) * rsx1 * gxg.y + gxb.y + (a1.y - muh1) * rsh1 * ghg.y + ghb.y + bi.y;
    g1.z = (x1.z - mux1) * rsx1 * gxg.z + gxb.z + (a1.z - muh1) * rsh1 * ghg.z + ghb.z + bi.z;
    g1.w = (x1.w - mux1) * rsx1 * gxg.w + gxb.w + (a1.w - muh1) * rsh1 * ghg.w + ghb.w + bi.w;

    *(float4*)&gex[0][4 * tid] = g0;
    *(float4*)&gex[1][4 * tid] = g1;
    __syncthreads();

    // ---- thread t gathers i,f,o,g for hidden unit t and updates state ----
    {
      const float gi0 = gex[0][tid],      gi1 = gex[1][tid];
      const float gf0 = gex[0][256 + tid], gf1 = gex[1][256 + tid];
      const float go0 = gex[0][512 + tid], go1 = gex[1][512 + tid];
      const float gg0 = gex[0][768 + tid], gg1 = gex[1][768 + tid];

      const float cn0 = fast_sigmoid(gf0) * c0r + fast_sigmoid(gi0) * fast_tanh(gg0);
      const float hn0 = fast_sigmoid(go0) * fast_tanh(cn0);
      const float cn1 = fast_sigmoid(gf1) * c1r + fast_sigmoid(gi1) * fast_tanh(gg1);
      const float hn1 = fast_sigmoid(go1) * fast_tanh(cn1);
      c0r = cn0; c1r = cn1;
      hbuf[0][tid] = hn0;
      hbuf[1][tid] = hn1;
      ys[((size_t)(t0 + t) * BB + b0 + 0) * HH + tid] = hn0;
      ys[((size_t)(t0 + t) * BB + b0 + 1) * HH + tid] = hn1;
    }
    __syncthreads();  // hbuf ready for next step
  }

  // write back running state (after last chunk this IS the hT/cT output)
  hsl[(b0 + 0) * HH + tid] = hbuf[0][tid];
  hsl[(b0 + 1) * HH + tid] = hbuf[1][tid];
  csl[(b0 + 0) * HH + tid] = c0r;
  csl[(b0 + 1) * HH + tid] = c1r;
}

extern "C" void kernel_launch(void* const* d_in, const int* in_sizes, int n_in,
                              void* d_out, int out_size, void* d_ws, size_t ws_size,
                              hipStream_t stream) {
  const float* x    = (const float*)d_in[0];
  const float* h0   = (const float*)d_in[1];
  const float* c0   = (const float*)d_in[2];
  const float* wx   = (const float*)d_in[3];
  const float* wh   = (const float*)d_in[4];
  const float* bias = (const float*)d_in[5];
  const float* gam  = (const float*)d_in[6];
  const float* bet  = (const float*)d_in[7];

  float* out  = (float*)d_out;
  float* ys_x = out;                                  // [S][B][H]: ys0 scratch, then final x
  float* hs   = out + (size_t)SS * BB * HH;           // [L][B][H] (doubles as running h state)
  float* cs   = hs + (size_t)NL * BB * HH;            // [L][B][H] (doubles as running c state)
  float* gxbuf = (float*)d_ws;                        // up to [S][B][NG] = 128 MiB

  // chunk the time axis to whatever the workspace can hold
  const size_t step_bytes = (size_t)BB * NG * sizeof(float);
  int T = (int)(ws_size / step_bytes);
  if (T > SS) T = SS;
  if (T < 1)  T = 1;

  const int nstate = NL * BB * HH;
  init_state<<<(nstate + 255) / 256, 256, 0, stream>>>(h0, c0, hs, cs, nstate);

  for (int l = 0; l < NL; ++l) {
    const float* Ain = (l == 0) ? x : ys_x;
    for (int t0 = 0; t0 < SS; t0 += T) {
      const int nt = (SS - t0 < T) ? (SS - t0) : T;
      const dim3 ggrid(NG / 128, nt);   // M = nt*BB rows, 128 rows/block
      gemm_gx<<<ggrid, 256, 0, stream>>>(Ain + (size_t)t0 * BB * INN,
                                         wx + (size_t)l * INN * NG, gxbuf);
      lstm_rec<<<BB / 2, 256, 0, stream>>>(
          gxbuf, wh + (size_t)l * HH * NG,
          hs + (size_t)l * BB * HH, cs + (size_t)l * BB * HH,
          gam + (size_t)l * 2 * NG, bet + (size_t)l * 2 * NG,
          bias + (size_t)l * NG, ys_x, t0, nt);
    }
  }
}